// Round 12
// baseline (373.079 us; speedup 1.0000x reference)
//
#include <hip/hip_runtime.h>
#include <hip/hip_fp16.h>

#define N_NODES 100000
#define N_EDGES 1600000
#define N_GRAPHS 2048
#define NFEAT 78
#define DIM 32
#define NLAYERS 5
#define OUTD 128
#define BN_EPS 1e-5f
#define NBUK 391                     // coarse buckets (256 nodes each)
#define BNODES 256                   // nodes per bucket
#define STRIDE 4608                  // slab per bucket (mean 4092, +8 sigma)
#define EPB 4096                     // edges per bfill block
#define NBLK ((N_EDGES + EPB - 1) / EPB)      // 391
#define NLB ((N_NODES + 63) / 64)             // 1563 layer blocks (64 nodes each)
#define NSLOTS3 ((NLB + 63) / 64)             // 25 partial-stats slots

// fp16 helpers
__device__ __forceinline__ float2 up2(unsigned u) {
    __half2 h = *reinterpret_cast<__half2*>(&u);
    return __half22float2(h);
}
__device__ __forceinline__ unsigned pk2(float a, float b) {
    __half2 h = __floats2half2_rn(a, b);
    return *reinterpret_cast<unsigned*>(&h);
}

// ---- prep: blocks [0,NBLK) bucket fill; rest gemm1 (x @ W1_0 -> fp16) ----
__global__ __launch_bounds__(256) void prep_kernel(
    const int* __restrict__ ei, int* __restrict__ bcnt, int* __restrict__ bdata,
    const float* __restrict__ x, const float* __restrict__ W1_0,
    unsigned short* __restrict__ y)
{
    __shared__ int cur[NBUK];
    __shared__ int gbl[NBUK];
    __shared__ float Wl[NFEAT * DIM];   // 9.75 KB
    int tid = threadIdx.x;

    if (blockIdx.x < NBLK) {
        int base = blockIdx.x * EPB;
        for (int i = tid; i < NBUK; i += 256) cur[i] = 0;
        __syncthreads();

        int ew[16], eb[16];
        const int4* s4 = (const int4*)ei;
        const int4* d4 = (const int4*)(ei + N_EDGES);
#pragma unroll
        for (int c = 0; c < 4; ++c) {
            int eidx = base + c * 1024 + tid * 4;
            if (eidx < N_EDGES) {
                int4 sv = s4[eidx >> 2];
                int4 dv = d4[eidx >> 2];
                ew[c*4+0] = sv.x | ((dv.x & 255) << 17); eb[c*4+0] = dv.x >> 8;
                ew[c*4+1] = sv.y | ((dv.y & 255) << 17); eb[c*4+1] = dv.y >> 8;
                ew[c*4+2] = sv.z | ((dv.z & 255) << 17); eb[c*4+2] = dv.z >> 8;
                ew[c*4+3] = sv.w | ((dv.w & 255) << 17); eb[c*4+3] = dv.w >> 8;
            } else {
                eb[c*4+0] = eb[c*4+1] = eb[c*4+2] = eb[c*4+3] = -1;
                ew[c*4+0] = ew[c*4+1] = ew[c*4+2] = ew[c*4+3] = 0;
            }
        }
        int slot[16];
#pragma unroll
        for (int k = 0; k < 16; ++k)
            slot[k] = (eb[k] >= 0) ? atomicAdd(&cur[eb[k]], 1) : 0;
        __syncthreads();
        for (int b = tid; b < NBUK; b += 256) {
            int c = cur[b];
            gbl[b] = (c > 0) ? atomicAdd(&bcnt[b], c) : 0;
        }
        __syncthreads();
#pragma unroll
        for (int k = 0; k < 16; ++k) {
            int b = eb[k];
            if (b >= 0) {
                int pos = gbl[b] + slot[k];
                if (pos < STRIDE) bdata[b * STRIDE + pos] = ew[k];
            }
        }
    } else {
        for (int i = tid; i < NFEAT * DIM; i += 256) Wl[i] = W1_0[i];
        __syncthreads();
        int t = (blockIdx.x - NBLK) * 256 + tid;
        int row = t >> 3;
        int c0 = (t & 7) * 4;
        float a0 = 0.f, a1 = 0.f, a2 = 0.f, a3 = 0.f;
        const float* hr = x + (long)row * NFEAT;
        for (int k = 0; k < NFEAT; ++k) {
            float xv = hr[k];
            a0 = fmaf(xv, Wl[k * DIM + c0 + 0], a0);
            a1 = fmaf(xv, Wl[k * DIM + c0 + 1], a1);
            a2 = fmaf(xv, Wl[k * DIM + c0 + 2], a2);
            a3 = fmaf(xv, Wl[k * DIM + c0 + 3], a3);
        }
        ((uint2*)y)[(long)row * 8 + (t & 7)] = make_uint2(pk2(a0, a1), pk2(a2, a3));
    }
}

// ---- bscan: exclusive scan of 391 bucket totals -> bbase[0..391] ----
__global__ __launch_bounds__(512) void bscan_kernel(
    const int* __restrict__ bcnt, int* __restrict__ bbase)
{
    __shared__ int sd[512];
    int t = threadIdx.x;
    int v = (t < NBUK) ? min(bcnt[t], STRIDE) : 0;
    sd[t] = v; __syncthreads();
    for (int off = 1; off < 512; off <<= 1) {
        int a = (t >= off) ? sd[t - off] : 0;
        __syncthreads();
        sd[t] += a;
        __syncthreads();
    }
    if (t < NBUK) bbase[t + 1] = sd[t];
    if (t == 0) bbase[0] = 0;
}

// ---- cfill2: per-bucket LDS counting sort -> flat CSR (edge_src, offs) ----
__global__ __launch_bounds__(256) void cfill2_kernel(
    const int* __restrict__ bcnt, const int* __restrict__ bbase,
    const int* __restrict__ bdata, int* __restrict__ edge_src,
    int* __restrict__ offs)
{
    __shared__ int sorted[STRIDE];          // 18.4 KB
    __shared__ int cnt[BNODES], off[BNODES], cur[BNODES];
    int b = blockIdx.x, tid = threadIdx.x;
    int n = min(bcnt[b], STRIDE);
    int gb = bbase[b];
    const int* slab = bdata + (long)b * STRIDE;

    if (tid < BNODES) cnt[tid] = 0;
    __syncthreads();
    for (int i = tid; i < n; i += 256)
        atomicAdd(&cnt[slab[i] >> 17], 1);
    __syncthreads();
    int t = tid;
    if (t < BNODES) off[t] = cnt[t];
    __syncthreads();
    for (int o = 1; o < BNODES; o <<= 1) {
        int a = (t >= o && t < BNODES) ? off[t - o] : 0;
        __syncthreads();
        if (t < BNODES) off[t] += a;
        __syncthreads();
    }
    if (t < BNODES) {
        int excl = off[t] - cnt[t];
        off[t] = excl;
        cur[t] = excl;
        int node = b * BNODES + t;
        if (node <= N_NODES) offs[node] = gb + excl;
    }
    __syncthreads();
    for (int i = tid; i < n; i += 256) {
        int w = slab[i];
        int pos = atomicAdd(&cur[w >> 17], 1);
        sorted[pos] = w & 0x1FFFF;
    }
    __syncthreads();
    for (int i = tid; i < n; i += 256)
        edge_src[gb + i] = sorted[i];
}

// ---- fused layer: 64 nodes/block, 2 nodes/lane-group (ILP-2 gather).
//      Prologue (MM): reduce prev-layer partial -> BN scale/shift, fold W1.
//      zs reused in-place for srow (wave-private rows, same-wave DS order). ----
template<bool MM>
__global__ __launch_bounds__(256) void layer_kernel(
    const int* __restrict__ offs, const int* __restrict__ edge_src,
    const unsigned short* __restrict__ zin,
    const float* __restrict__ W1g,          // unscaled next W1 (MM only)
    const float* __restrict__ partial_prev, // prev stats (MM only)
    const float* __restrict__ gprev, const float* __restrict__ bprev,
    const float* __restrict__ b1v,
    const float* __restrict__ W2, const float* __restrict__ b2v,
    unsigned short* __restrict__ zout, float* __restrict__ partial)
{
    __shared__ float W1l[DIM * DIM];
    __shared__ float W2l[DIM * DIM];
    __shared__ float zs[64][36];           // 9 KB; also prologue scratch
    __shared__ float b1l[DIM], b2l[DIM], cl[DIM];
    __shared__ float sscl[DIM], sshl[DIM];
    __shared__ float psum[DIM], psq[DIM];

    int tid = threadIdx.x;
    float* red = &zs[0][0];

    for (int i = tid; i < DIM * DIM; i += 256) W2l[i] = W2[i];
    if (tid < DIM) {
        b1l[tid] = b1v[tid]; b2l[tid] = b2v[tid];
        psum[tid] = 0.f; psq[tid] = 0.f;
    }
    if (MM) {
        int c = tid & 63, chunk = tid >> 6;
        float a = 0.f;
        for (int p = chunk; p < NSLOTS3; p += 4) a += partial_prev[p * 64 + c];
        red[tid] = a;
        __syncthreads();
        if (tid < 64) red[tid] = red[tid] + red[tid+64] + red[tid+128] + red[tid+192];
        __syncthreads();
        if (tid < DIM) {
            const float invN = 1.0f / (float)N_NODES;
            float S = red[tid], Q = red[tid + DIM];
            float mu = S * invN;
            float var = Q * invN - mu * mu;
            float sc = gprev[tid] * rsqrtf(var + BN_EPS);
            sscl[tid] = sc;
            sshl[tid] = bprev[tid] - mu * sc;
        }
        __syncthreads();
        for (int i = tid; i < DIM * DIM; i += 256) W1l[i] = sscl[i >> 5] * W1g[i];
        if (tid < DIM) {
            float cv = 0.f;
            for (int k = 0; k < DIM; ++k) cv = fmaf(sshl[k], W1g[k * DIM + tid], cv);
            cl[tid] = cv;
        }
    }
    __syncthreads();   // weights ready; zs scratch free

    int ln = tid >> 3, p = tid & 7;
    int c0 = p * 4;
    int nb = blockIdx.x * 64;
    int nA = nb + ln;              // always < N_NODES
    int nB = nb + 32 + ln;
    bool vB = nB < N_NODES;
    int begA = offs[nA], endA = offs[nA + 1];
    int begB = 0, endB = 0;
    if (vB) { begB = offs[nB]; endB = offs[nB + 1]; }
    int degA = endA - begA, degB = endB - begB;
    const uint2* zb = (const uint2*)zin;

    // phase 1: dual-chain gather
    uint2 svA = zb[(long)nA * 8 + p];
    float2 f;
    f = up2(svA.x); float a0 = f.x, a1 = f.y;
    f = up2(svA.y); float a2 = f.x, a3 = f.y;
    float g0 = 0.f, g1 = 0.f, g2 = 0.f, g3 = 0.f;
    if (vB) {
        uint2 svB = zb[(long)nB * 8 + p];
        f = up2(svB.x); g0 = f.x; g1 = f.y;
        f = up2(svB.y); g2 = f.x; g3 = f.y;
    }
    int eA = begA, eB = begB;
    for (; eA + 4 <= endA && eB + 4 <= endB; eA += 4, eB += 4) {
        int sA0 = edge_src[eA+0], sA1 = edge_src[eA+1];
        int sA2 = edge_src[eA+2], sA3 = edge_src[eA+3];
        int sB0 = edge_src[eB+0], sB1 = edge_src[eB+1];
        int sB2 = edge_src[eB+2], sB3 = edge_src[eB+3];
        uint2 vA0 = zb[(long)sA0*8+p], vA1 = zb[(long)sA1*8+p];
        uint2 vA2 = zb[(long)sA2*8+p], vA3 = zb[(long)sA3*8+p];
        uint2 vB0 = zb[(long)sB0*8+p], vB1 = zb[(long)sB1*8+p];
        uint2 vB2 = zb[(long)sB2*8+p], vB3 = zb[(long)sB3*8+p];
        f = up2(vA0.x); a0 += f.x; a1 += f.y;  f = up2(vA0.y); a2 += f.x; a3 += f.y;
        f = up2(vA1.x); a0 += f.x; a1 += f.y;  f = up2(vA1.y); a2 += f.x; a3 += f.y;
        f = up2(vA2.x); a0 += f.x; a1 += f.y;  f = up2(vA2.y); a2 += f.x; a3 += f.y;
        f = up2(vA3.x); a0 += f.x; a1 += f.y;  f = up2(vA3.y); a2 += f.x; a3 += f.y;
        f = up2(vB0.x); g0 += f.x; g1 += f.y;  f = up2(vB0.y); g2 += f.x; g3 += f.y;
        f = up2(vB1.x); g0 += f.x; g1 += f.y;  f = up2(vB1.y); g2 += f.x; g3 += f.y;
        f = up2(vB2.x); g0 += f.x; g1 += f.y;  f = up2(vB2.y); g2 += f.x; g3 += f.y;
        f = up2(vB3.x); g0 += f.x; g1 += f.y;  f = up2(vB3.y); g2 += f.x; g3 += f.y;
    }
    for (; eA + 4 <= endA; eA += 4) {
        int s0 = edge_src[eA+0], s1 = edge_src[eA+1];
        int s2 = edge_src[eA+2], s3 = edge_src[eA+3];
        uint2 v0 = zb[(long)s0*8+p], v1 = zb[(long)s1*8+p];
        uint2 v2 = zb[(long)s2*8+p], v3 = zb[(long)s3*8+p];
        f = up2(v0.x); a0 += f.x; a1 += f.y;  f = up2(v0.y); a2 += f.x; a3 += f.y;
        f = up2(v1.x); a0 += f.x; a1 += f.y;  f = up2(v1.y); a2 += f.x; a3 += f.y;
        f = up2(v2.x); a0 += f.x; a1 += f.y;  f = up2(v2.y); a2 += f.x; a3 += f.y;
        f = up2(v3.x); a0 += f.x; a1 += f.y;  f = up2(v3.y); a2 += f.x; a3 += f.y;
    }
    for (; eA < endA; ++eA) {
        uint2 v = zb[(long)edge_src[eA]*8+p];
        f = up2(v.x); a0 += f.x; a1 += f.y;
        f = up2(v.y); a2 += f.x; a3 += f.y;
    }
    for (; eB + 4 <= endB; eB += 4) {
        int s0 = edge_src[eB+0], s1 = edge_src[eB+1];
        int s2 = edge_src[eB+2], s3 = edge_src[eB+3];
        uint2 v0 = zb[(long)s0*8+p], v1 = zb[(long)s1*8+p];
        uint2 v2 = zb[(long)s2*8+p], v3 = zb[(long)s3*8+p];
        f = up2(v0.x); g0 += f.x; g1 += f.y;  f = up2(v0.y); g2 += f.x; g3 += f.y;
        f = up2(v1.x); g0 += f.x; g1 += f.y;  f = up2(v1.y); g2 += f.x; g3 += f.y;
        f = up2(v2.x); g0 += f.x; g1 += f.y;  f = up2(v2.y); g2 += f.x; g3 += f.y;
        f = up2(v3.x); g0 += f.x; g1 += f.y;  f = up2(v3.y); g2 += f.x; g3 += f.y;
    }
    for (; eB < endB; ++eB) {
        uint2 v = zb[(long)edge_src[eB]*8+p];
        f = up2(v.x); g0 += f.x; g1 += f.y;
        f = up2(v.y); g2 += f.x; g3 += f.y;
    }
    *(float4*)&zs[ln][c0]      = make_float4(a0, a1, a2, a3);
    *(float4*)&zs[ln + 32][c0] = make_float4(g0, g1, g2, g3);
    // no barrier: rows wave-private, same-wave DS order

    // phase 2: s = zsum@W1' + (deg+1)*c + b1 (or zsum + b1), relu; in-place
    float tA[4], tB[4];
    if (MM) {
        tA[0]=tA[1]=tA[2]=tA[3]=0.f; tB[0]=tB[1]=tB[2]=tB[3]=0.f;
#pragma unroll
        for (int k = 0; k < DIM; ++k) {
            float w0 = W1l[k * DIM + c0 + 0], w1 = W1l[k * DIM + c0 + 1];
            float w2 = W1l[k * DIM + c0 + 2], w3 = W1l[k * DIM + c0 + 3];
            float zk = zs[ln][k];
            tA[0] = fmaf(zk, w0, tA[0]); tA[1] = fmaf(zk, w1, tA[1]);
            tA[2] = fmaf(zk, w2, tA[2]); tA[3] = fmaf(zk, w3, tA[3]);
            float wk = zs[ln + 32][k];
            tB[0] = fmaf(wk, w0, tB[0]); tB[1] = fmaf(wk, w1, tB[1]);
            tB[2] = fmaf(wk, w2, tB[2]); tB[3] = fmaf(wk, w3, tB[3]);
        }
        float dA = (float)(degA + 1), dB = (float)(degB + 1);
#pragma unroll
        for (int j = 0; j < 4; ++j) {
            tA[j] = fmaxf(fmaf(dA, cl[c0 + j], tA[j]) + b1l[c0 + j], 0.f);
            tB[j] = fmaxf(fmaf(dB, cl[c0 + j], tB[j]) + b1l[c0 + j], 0.f);
        }
    } else {
        tA[0] = fmaxf(a0 + b1l[c0 + 0], 0.f); tA[1] = fmaxf(a1 + b1l[c0 + 1], 0.f);
        tA[2] = fmaxf(a2 + b1l[c0 + 2], 0.f); tA[3] = fmaxf(a3 + b1l[c0 + 3], 0.f);
        tB[0] = fmaxf(g0 + b1l[c0 + 0], 0.f); tB[1] = fmaxf(g1 + b1l[c0 + 1], 0.f);
        tB[2] = fmaxf(g2 + b1l[c0 + 2], 0.f); tB[3] = fmaxf(g3 + b1l[c0 + 3], 0.f);
    }
    *(float4*)&zs[ln][c0]      = make_float4(tA[0], tA[1], tA[2], tA[3]);
    *(float4*)&zs[ln + 32][c0] = make_float4(tB[0], tB[1], tB[2], tB[3]);

    // phase 3: z = relu(s@W2 + b2)
    float zA[4] = { b2l[c0+0], b2l[c0+1], b2l[c0+2], b2l[c0+3] };
    float zB[4] = { b2l[c0+0], b2l[c0+1], b2l[c0+2], b2l[c0+3] };
#pragma unroll
    for (int k = 0; k < DIM; ++k) {
        float w0 = W2l[k * DIM + c0 + 0], w1 = W2l[k * DIM + c0 + 1];
        float w2 = W2l[k * DIM + c0 + 2], w3 = W2l[k * DIM + c0 + 3];
        float sk = zs[ln][k];
        zA[0] = fmaf(sk, w0, zA[0]); zA[1] = fmaf(sk, w1, zA[1]);
        zA[2] = fmaf(sk, w2, zA[2]); zA[3] = fmaf(sk, w3, zA[3]);
        float rk = zs[ln + 32][k];
        zB[0] = fmaf(rk, w0, zB[0]); zB[1] = fmaf(rk, w1, zB[1]);
        zB[2] = fmaf(rk, w2, zB[2]); zB[3] = fmaf(rk, w3, zB[3]);
    }
#pragma unroll
    for (int j = 0; j < 4; ++j) {
        zA[j] = fmaxf(zA[j], 0.f);
        zB[j] = fmaxf(zB[j], 0.f);
    }
    ((uint2*)zout)[(long)nA * 8 + p] = make_uint2(pk2(zA[0], zA[1]), pk2(zA[2], zA[3]));
    if (vB)
        ((uint2*)zout)[(long)nB * 8 + p] = make_uint2(pk2(zB[0], zB[1]), pk2(zB[2], zB[3]));
    else { zB[0] = zB[1] = zB[2] = zB[3] = 0.f; }

    // BN partial stats (A+B combined per lane)
    float sv[4], sq[4];
#pragma unroll
    for (int j = 0; j < 4; ++j) {
        sv[j] = zA[j] + zB[j];
        sq[j] = zA[j]*zA[j] + zB[j]*zB[j];
    }
#pragma unroll
    for (int off = 8; off < 64; off <<= 1) {
#pragma unroll
        for (int j = 0; j < 4; ++j) {
            sv[j] += __shfl_xor(sv[j], off, 64);
            sq[j] += __shfl_xor(sq[j], off, 64);
        }
    }
    if ((tid & 63) < 8) {
#pragma unroll
        for (int j = 0; j < 4; ++j) {
            atomicAdd(&psum[c0 + j], sv[j]);
            atomicAdd(&psq[c0 + j], sq[j]);
        }
    }
    __syncthreads();
    if (tid < 2 * DIM) {
        float v = (tid < DIM) ? psum[tid] : psq[tid - DIM];
        atomicAdd(&partial[(long)(blockIdx.x >> 6) * 2 * DIM + tid], v);
    }
}

// ------- pool: RAW sums + per-graph node counts (no BN dependency) -------
__global__ __launch_bounds__(256) void pool_kernel(
    const unsigned short* __restrict__ z, const int* __restrict__ batch,
    float* __restrict__ praw, float* __restrict__ cntg)
{
    __shared__ float acc[32][32];
    __shared__ float cntL[32];
    __shared__ int slot[32];
    __shared__ int segg[32];
    __shared__ int nsegS;
    int tid = threadIdx.x;
    for (int i = tid; i < 1024; i += 256) ((float*)acc)[i] = 0.f;
    if (tid < 32) cntL[tid] = 0.f;
    int nodeBase = blockIdx.x * 32;
    if (tid < 32) {
        int nd = nodeBase + tid;
        int gv = batch[nd];
        int flag = (tid == 0) ? 1 : (gv != batch[nd - 1]);
        unsigned long long m = __ballot(flag);
        int s = __popcll(m & ((2ull << tid) - 1ull)) - 1;
        slot[tid] = s;
        if (flag) segg[s] = gv;
        if (tid == 0) nsegS = __popcll(m);
    }
    __syncthreads();

    int ln = tid >> 3;
    int p = tid & 7;
    long node = nodeBase + ln;
    uint2 u = ((const uint2*)z)[node * 8 + p];
    int c = p * 4;
    float2 f01 = up2(u.x), f23 = up2(u.y);
    int s = slot[ln];
    atomicAdd(&acc[s][c+0], f01.x);
    atomicAdd(&acc[s][c+1], f01.y);
    atomicAdd(&acc[s][c+2], f23.x);
    atomicAdd(&acc[s][c+3], f23.y);
    if (p == 0) atomicAdd(&cntL[s], 1.f);
    __syncthreads();

    int total = nsegS * 32;
    for (int i = tid; i < total; i += 256) {
        int r = i >> 5, dd = i & 31;
        float val = acc[r][dd];
        if (val != 0.f) atomicAdd(&praw[(long)segg[r] * DIM + dd], val);
    }
    if (tid < nsegS) atomicAdd(&cntg[segg[tid]], cntL[tid]);
}

// ---- fc: prologue computes layer-4 BN from partial4, then
//      out = relu(bfc + cnt*(shl@Wfc) + (scl.*praw)@Wfc) ----
__global__ __launch_bounds__(256) void fc_kernel(
    const float* __restrict__ praw, const float* __restrict__ cntg,
    const float* __restrict__ partial4,
    const float* __restrict__ g4, const float* __restrict__ be4,
    const float* __restrict__ Wfc, const float* __restrict__ bfc,
    float* __restrict__ out)
{
    __shared__ float Wl[DIM * OUTD];   // 16 KB
    __shared__ float red[256];
    __shared__ float sscl[DIM], sshl[DIM], dvec[OUTD];
    int tid = threadIdx.x;
    for (int i = tid; i < DIM * OUTD; i += 256) Wl[i] = Wfc[i];
    {
        int c = tid & 63, chunk = tid >> 6;
        float a = 0.f;
        for (int p = chunk; p < NSLOTS3; p += 4) a += partial4[p * 64 + c];
        red[tid] = a;
    }
    __syncthreads();
    if (tid < 64) red[tid] = red[tid] + red[tid+64] + red[tid+128] + red[tid+192];
    __syncthreads();
    if (tid < DIM) {
        const float invN = 1.0f / (float)N_NODES;
        float S = red[tid], Q = red[tid + DIM];
        float mu = S * invN;
        float var = Q * invN - mu * mu;
        float sc = g4[tid] * rsqrtf(var + BN_EPS);
        sscl[tid] = sc;
        sshl[tid] = be4[tid] - mu * sc;
    }
    __syncthreads();
    if (tid < OUTD) {
        float dv = 0.f;
        for (int k = 0; k < DIM; ++k) dv = fmaf(sshl[k], Wl[k * OUTD + tid], dv);
        dvec[tid] = dv;
    }
    __syncthreads();
    int t = blockIdx.x * 256 + tid;
    int g = t >> 7;
    int o = t & (OUTD - 1);
    float acc = bfc[o] + cntg[g] * dvec[o];
    const float* pr = praw + (long)g * DIM;
#pragma unroll
    for (int k = 0; k < DIM; ++k)
        acc = fmaf(sscl[k] * pr[k], Wl[k * OUTD + o], acc);
    out[t] = fmaxf(acc, 0.f);
}

extern "C" void kernel_launch(void* const* d_in, const int* in_sizes, int n_in,
                              void* d_out, int out_size, void* d_ws, size_t ws_size,
                              hipStream_t stream) {
    const float* x      = (const float*)d_in[0];
    const int*   ei     = (const int*)  d_in[1];
    const int*   batch  = (const int*)  d_in[2];
    const float* W1_0   = (const float*)d_in[3];
    const float* W1_rest= (const float*)d_in[4];
    const float* b1     = (const float*)d_in[5];
    const float* W2     = (const float*)d_in[6];
    const float* b2     = (const float*)d_in[7];
    const float* gamma  = (const float*)d_in[8];
    const float* beta   = (const float*)d_in[9];
    const float* Wfc    = (const float*)d_in[10];
    const float* bfc    = (const float*)d_in[11];
    float* out = (float*)d_out;

    int* wsi = (int*)d_ws;
    const size_t nf = (size_t)N_NODES * DIM;                   // 3.2M elems
    const size_t BD = (size_t)NBUK * STRIDE;                   // 1,801,728 ints
    const size_t PSTRIDE = (size_t)NSLOTS3 * 2 * DIM;          // 1600 floats
    int*   bdata  = wsi;
    unsigned short* zfpA = (unsigned short*)(wsi + BD);        // 6.4 MB
    unsigned short* zfpB = zfpA + nf;                          // 6.4 MB
    int*   edge_src = (int*)(zfpB + nf);                       // 1.6M ints
    int*   offs   = edge_src + N_EDGES;                        // 100,001
    int*   bcnt   = offs + (N_NODES + 1);                      // 391
    int*   bbase  = bcnt + NBUK;                               // 392
    float* praw   = (float*)(bbase + NBUK + 1);                // 65,536
    float* cntg   = praw + (size_t)N_GRAPHS * DIM;             // 2,048
    float* partial= cntg + N_GRAPHS;                           // 5*1600

    hipMemsetAsync(praw, 0,
        ((size_t)N_GRAPHS * DIM + N_GRAPHS + NLAYERS * PSTRIDE) * sizeof(float),
        stream);
    hipMemsetAsync(bcnt, 0, (size_t)NBUK * sizeof(int), stream);

    const int grpBlocks = (N_NODES * 8) / 256;                 // 3125

    // prep: bucket fill (391 blocks) || gemm1 (3125 blocks)
    prep_kernel<<<NBLK + grpBlocks, 256, 0, stream>>>(
        ei, bcnt, bdata, x, W1_0, zfpA);
    bscan_kernel<<<1, 512, 0, stream>>>(bcnt, bbase);
    cfill2_kernel<<<NBUK, 256, 0, stream>>>(bcnt, bbase, bdata, edge_src, offs);

    // layer 0: gather y0, no matmul fold
    layer_kernel<false><<<NLB, 256, 0, stream>>>(
        offs, edge_src, zfpA, nullptr, nullptr, nullptr, nullptr,
        b1, W2, b2, zfpB, partial);

    // layers 1..4: prologue folds prev BN into W1
    const unsigned short* zi = zfpB;
    unsigned short* zo = zfpA;
    for (int i = 1; i < NLAYERS; ++i) {
        layer_kernel<true><<<NLB, 256, 0, stream>>>(
            offs, edge_src, zi,
            W1_rest + (size_t)(i - 1) * DIM * DIM,
            partial + (size_t)(i - 1) * PSTRIDE,
            gamma + (i - 1) * DIM, beta + (i - 1) * DIM,
            b1 + i * DIM, W2 + (size_t)i * DIM * DIM, b2 + i * DIM,
            zo, partial + (size_t)i * PSTRIDE);
        const unsigned short* tmp = zi; zi = zo; zo = (unsigned short*)tmp;
    }

    // pool raw sums + counts (no BN dependency), then fc applies layer-4 BN
    pool_kernel<<<N_NODES / 32, 256, 0, stream>>>(zi, batch, praw, cntg);
    fc_kernel<<<(N_GRAPHS * OUTD) / 256, 256, 0, stream>>>(
        praw, cntg, partial + (size_t)(NLAYERS - 1) * PSTRIDE,
        gamma + (NLAYERS - 1) * DIM, beta + (NLAYERS - 1) * DIM,
        Wfc, bfc, out);
}

// Round 13
// 302.447 us; speedup vs baseline: 1.2335x; 1.2335x over previous
//
#include <hip/hip_runtime.h>
#include <hip/hip_fp16.h>

#define N_NODES 100000
#define N_EDGES 1600000
#define N_GRAPHS 2048
#define NFEAT 78
#define DIM 32
#define NLAYERS 5
#define OUTD 128
#define BN_EPS 1e-5f
#define NPB 32                       // nodes per layer-block
#define NBUK 391                     // coarse buckets (256 nodes each)
#define BNODES 256                   // nodes per bucket
#define STRIDE 4608                  // slab per bucket (mean 4092, +8 sigma)
#define EPB 4096                     // edges per bfill block
#define NBLK ((N_EDGES + EPB - 1) / EPB)      // 391
#define NSLOTS2 ((N_NODES / NPB + 63) / 64)   // 49 partial-stats slots

// fp16 helpers
__device__ __forceinline__ float2 up2(unsigned u) {
    __half2 h = *reinterpret_cast<__half2*>(&u);
    return __half22float2(h);
}
__device__ __forceinline__ unsigned pk2(float a, float b) {
    __half2 h = __floats2half2_rn(a, b);
    return *reinterpret_cast<unsigned*>(&h);
}

// ---- prep: blocks [0,NBLK) bucket fill; rest gemm1 (x @ W1_0 -> fp16) ----
__global__ __launch_bounds__(256) void prep_kernel(
    const int* __restrict__ ei, int* __restrict__ bcnt, int* __restrict__ bdata,
    const float* __restrict__ x, const float* __restrict__ W1_0,
    unsigned short* __restrict__ y)
{
    __shared__ int cur[NBUK];
    __shared__ int gbl[NBUK];
    __shared__ float Wl[NFEAT * DIM];   // 9.75 KB
    int tid = threadIdx.x;

    if (blockIdx.x < NBLK) {
        int base = blockIdx.x * EPB;
        for (int i = tid; i < NBUK; i += 256) cur[i] = 0;
        __syncthreads();

        int ew[16], eb[16];
        const int4* s4 = (const int4*)ei;
        const int4* d4 = (const int4*)(ei + N_EDGES);
#pragma unroll
        for (int c = 0; c < 4; ++c) {
            int eidx = base + c * 1024 + tid * 4;
            if (eidx < N_EDGES) {
                int4 sv = s4[eidx >> 2];
                int4 dv = d4[eidx >> 2];
                ew[c*4+0] = sv.x | ((dv.x & 255) << 17); eb[c*4+0] = dv.x >> 8;
                ew[c*4+1] = sv.y | ((dv.y & 255) << 17); eb[c*4+1] = dv.y >> 8;
                ew[c*4+2] = sv.z | ((dv.z & 255) << 17); eb[c*4+2] = dv.z >> 8;
                ew[c*4+3] = sv.w | ((dv.w & 255) << 17); eb[c*4+3] = dv.w >> 8;
            } else {
                eb[c*4+0] = eb[c*4+1] = eb[c*4+2] = eb[c*4+3] = -1;
                ew[c*4+0] = ew[c*4+1] = ew[c*4+2] = ew[c*4+3] = 0;
            }
        }
        int slot[16];
#pragma unroll
        for (int k = 0; k < 16; ++k)
            slot[k] = (eb[k] >= 0) ? atomicAdd(&cur[eb[k]], 1) : 0;
        __syncthreads();
        for (int b = tid; b < NBUK; b += 256) {
            int c = cur[b];
            gbl[b] = (c > 0) ? atomicAdd(&bcnt[b], c) : 0;
        }
        __syncthreads();
#pragma unroll
        for (int k = 0; k < 16; ++k) {
            int b = eb[k];
            if (b >= 0) {
                int pos = gbl[b] + slot[k];
                if (pos < STRIDE) bdata[b * STRIDE + pos] = ew[k];
            }
        }
    } else {
        for (int i = tid; i < NFEAT * DIM; i += 256) Wl[i] = W1_0[i];
        __syncthreads();
        int t = (blockIdx.x - NBLK) * 256 + tid;
        int row = t >> 3;
        int c0 = (t & 7) * 4;
        float a0 = 0.f, a1 = 0.f, a2 = 0.f, a3 = 0.f;
        const float* hr = x + (long)row * NFEAT;
        for (int k = 0; k < NFEAT; ++k) {
            float xv = hr[k];
            a0 = fmaf(xv, Wl[k * DIM + c0 + 0], a0);
            a1 = fmaf(xv, Wl[k * DIM + c0 + 1], a1);
            a2 = fmaf(xv, Wl[k * DIM + c0 + 2], a2);
            a3 = fmaf(xv, Wl[k * DIM + c0 + 3], a3);
        }
        ((uint2*)y)[(long)row * 8 + (t & 7)] = make_uint2(pk2(a0, a1), pk2(a2, a3));
    }
}

// ---- bscan: exclusive scan of 391 bucket totals -> bbase[0..391] ----
__global__ __launch_bounds__(512) void bscan_kernel(
    const int* __restrict__ bcnt, int* __restrict__ bbase)
{
    __shared__ int sd[512];
    int t = threadIdx.x;
    int v = (t < NBUK) ? min(bcnt[t], STRIDE) : 0;
    sd[t] = v; __syncthreads();
    for (int off = 1; off < 512; off <<= 1) {
        int a = (t >= off) ? sd[t - off] : 0;
        __syncthreads();
        sd[t] += a;
        __syncthreads();
    }
    if (t < NBUK) bbase[t + 1] = sd[t];
    if (t == 0) bbase[0] = 0;
}

// ---- cfill2: per-bucket LDS counting sort -> flat CSR (edge_src, offs) ----
__global__ __launch_bounds__(256) void cfill2_kernel(
    const int* __restrict__ bcnt, const int* __restrict__ bbase,
    const int* __restrict__ bdata, int* __restrict__ edge_src,
    int* __restrict__ offs)
{
    __shared__ int sorted[STRIDE];          // 18.4 KB
    __shared__ int cnt[BNODES], off[BNODES], cur[BNODES];
    int b = blockIdx.x, tid = threadIdx.x;
    int n = min(bcnt[b], STRIDE);
    int gb = bbase[b];
    const int* slab = bdata + (long)b * STRIDE;

    if (tid < BNODES) cnt[tid] = 0;
    __syncthreads();
    for (int i = tid; i < n; i += 256)
        atomicAdd(&cnt[slab[i] >> 17], 1);
    __syncthreads();
    int t = tid;
    if (t < BNODES) off[t] = cnt[t];
    __syncthreads();
    for (int o = 1; o < BNODES; o <<= 1) {
        int a = (t >= o && t < BNODES) ? off[t - o] : 0;
        __syncthreads();
        if (t < BNODES) off[t] += a;
        __syncthreads();
    }
    if (t < BNODES) {
        int excl = off[t] - cnt[t];
        off[t] = excl;
        cur[t] = excl;
        int node = b * BNODES + t;
        if (node <= N_NODES) offs[node] = gb + excl;
    }
    __syncthreads();
    for (int i = tid; i < n; i += 256) {
        int w = slab[i];
        int pos = atomicAdd(&cur[w >> 17], 1);
        sorted[pos] = w & 0x1FFFF;
    }
    __syncthreads();
    for (int i = tid; i < n; i += 256)
        edge_src[gb + i] = sorted[i];
}

// ---- fused layer: 32 nodes/block, 8 lanes/node, single gather chain.
//      Prologue (MM): reduce prev partial -> BN scale/shift, fold into W1.
//      zs reused in-place (wave-lockstep: k-loop reads precede stores). ----
template<bool MM>
__global__ __launch_bounds__(256) void layer_kernel(
    const int* __restrict__ offs, const int* __restrict__ edge_src,
    const unsigned short* __restrict__ zin,
    const float* __restrict__ W1g,          // unscaled W1 (MM only)
    const float* __restrict__ partial_prev, // prev stats (MM only)
    const float* __restrict__ gprev, const float* __restrict__ bprev,
    const float* __restrict__ b1v,
    const float* __restrict__ W2, const float* __restrict__ b2v,
    unsigned short* __restrict__ zout, float* __restrict__ partial)
{
    __shared__ float W1l[DIM * DIM];       // 4 KB (MM only)
    __shared__ float W2l[DIM * DIM];       // 4 KB
    __shared__ float zs[NPB][36];          // 4.5 KB; also prologue scratch
    __shared__ float b1l[DIM], b2l[DIM], cl[DIM];
    __shared__ float sscl[DIM], sshl[DIM];
    __shared__ float psum[DIM], psq[DIM];

    int tid = threadIdx.x;
    float* red = &zs[0][0];

    for (int i = tid; i < DIM * DIM; i += 256) W2l[i] = W2[i];
    if (tid < DIM) {
        b1l[tid] = b1v[tid]; b2l[tid] = b2v[tid];
        psum[tid] = 0.f; psq[tid] = 0.f;
    }
    if (MM) {
        int c = tid & 63, chunk = tid >> 6;
        float a = 0.f;
        for (int p = chunk; p < NSLOTS2; p += 4) a += partial_prev[p * 64 + c];
        red[tid] = a;
        __syncthreads();
        if (tid < 64) red[tid] = red[tid] + red[tid+64] + red[tid+128] + red[tid+192];
        __syncthreads();
        if (tid < DIM) {
            const float invN = 1.0f / (float)N_NODES;
            float S = red[tid], Q = red[tid + DIM];
            float mu = S * invN;
            float var = Q * invN - mu * mu;
            float sc = gprev[tid] * rsqrtf(var + BN_EPS);
            sscl[tid] = sc;
            sshl[tid] = bprev[tid] - mu * sc;
        }
        __syncthreads();
        for (int i = tid; i < DIM * DIM; i += 256) W1l[i] = sscl[i >> 5] * W1g[i];
        if (tid < DIM) {
            float cv = 0.f;
            for (int k = 0; k < DIM; ++k) cv = fmaf(sshl[k], W1g[k * DIM + tid], cv);
            cl[tid] = cv;
        }
    }
    __syncthreads();   // weights ready; zs scratch free

    int ln = tid >> 3, p = tid & 7;
    int c0 = p * 4;
    long node = (long)blockIdx.x * NPB + ln;
    int beg = offs[node], end = offs[node + 1];
    int deg = end - beg;
    const uint2* zb = (const uint2*)zin;

    // phase 1: gather (self + in-neighbors), unroll x8
    uint2 sv = zb[node * 8 + p];
    float2 f;
    f = up2(sv.x); float a0 = f.x, a1 = f.y;
    f = up2(sv.y); float a2 = f.x, a3 = f.y;
    int e = beg;
    for (; e + 8 <= end; e += 8) {
        uint2 v0 = zb[(long)edge_src[e + 0] * 8 + p];
        uint2 v1 = zb[(long)edge_src[e + 1] * 8 + p];
        uint2 v2 = zb[(long)edge_src[e + 2] * 8 + p];
        uint2 v3 = zb[(long)edge_src[e + 3] * 8 + p];
        uint2 v4 = zb[(long)edge_src[e + 4] * 8 + p];
        uint2 v5 = zb[(long)edge_src[e + 5] * 8 + p];
        uint2 v6 = zb[(long)edge_src[e + 6] * 8 + p];
        uint2 v7 = zb[(long)edge_src[e + 7] * 8 + p];
        f = up2(v0.x); a0 += f.x; a1 += f.y;  f = up2(v0.y); a2 += f.x; a3 += f.y;
        f = up2(v1.x); a0 += f.x; a1 += f.y;  f = up2(v1.y); a2 += f.x; a3 += f.y;
        f = up2(v2.x); a0 += f.x; a1 += f.y;  f = up2(v2.y); a2 += f.x; a3 += f.y;
        f = up2(v3.x); a0 += f.x; a1 += f.y;  f = up2(v3.y); a2 += f.x; a3 += f.y;
        f = up2(v4.x); a0 += f.x; a1 += f.y;  f = up2(v4.y); a2 += f.x; a3 += f.y;
        f = up2(v5.x); a0 += f.x; a1 += f.y;  f = up2(v5.y); a2 += f.x; a3 += f.y;
        f = up2(v6.x); a0 += f.x; a1 += f.y;  f = up2(v6.y); a2 += f.x; a3 += f.y;
        f = up2(v7.x); a0 += f.x; a1 += f.y;  f = up2(v7.y); a2 += f.x; a3 += f.y;
    }
    for (; e < end; ++e) {
        uint2 v = zb[(long)edge_src[e] * 8 + p];
        f = up2(v.x); a0 += f.x; a1 += f.y;
        f = up2(v.y); a2 += f.x; a3 += f.y;
    }
    *(float4*)&zs[ln][c0] = make_float4(a0, a1, a2, a3);
    // no barrier: zs row is wave-private (same-wave DS order)

    // phase 2: s = zsum@W1' + (deg+1)*c + b1 (or zsum + b1), relu; in-place
    float t4[4];
    if (MM) {
        t4[0] = t4[1] = t4[2] = t4[3] = 0.f;
#pragma unroll
        for (int k = 0; k < DIM; ++k) {
            float zk = zs[ln][k];
            t4[0] = fmaf(zk, W1l[k * DIM + c0 + 0], t4[0]);
            t4[1] = fmaf(zk, W1l[k * DIM + c0 + 1], t4[1]);
            t4[2] = fmaf(zk, W1l[k * DIM + c0 + 2], t4[2]);
            t4[3] = fmaf(zk, W1l[k * DIM + c0 + 3], t4[3]);
        }
        float dp1 = (float)(deg + 1);
#pragma unroll
        for (int j = 0; j < 4; ++j)
            t4[j] = fmaxf(fmaf(dp1, cl[c0 + j], t4[j]) + b1l[c0 + j], 0.f);
    } else {
        t4[0] = fmaxf(a0 + b1l[c0 + 0], 0.f);
        t4[1] = fmaxf(a1 + b1l[c0 + 1], 0.f);
        t4[2] = fmaxf(a2 + b1l[c0 + 2], 0.f);
        t4[3] = fmaxf(a3 + b1l[c0 + 3], 0.f);
    }
    *(float4*)&zs[ln][c0] = make_float4(t4[0], t4[1], t4[2], t4[3]);
    // lockstep wave: all k-loop reads above complete before this store

    // phase 3: z = relu(s@W2 + b2), fp16 write + stats
    float zv[4] = { b2l[c0 + 0], b2l[c0 + 1], b2l[c0 + 2], b2l[c0 + 3] };
#pragma unroll
    for (int k = 0; k < DIM; ++k) {
        float sk = zs[ln][k];
        zv[0] = fmaf(sk, W2l[k * DIM + c0 + 0], zv[0]);
        zv[1] = fmaf(sk, W2l[k * DIM + c0 + 1], zv[1]);
        zv[2] = fmaf(sk, W2l[k * DIM + c0 + 2], zv[2]);
        zv[3] = fmaf(sk, W2l[k * DIM + c0 + 3], zv[3]);
    }
#pragma unroll
    for (int j = 0; j < 4; ++j) zv[j] = fmaxf(zv[j], 0.f);
    ((uint2*)zout)[node * 8 + p] = make_uint2(pk2(zv[0], zv[1]), pk2(zv[2], zv[3]));

    float sq[4];
#pragma unroll
    for (int j = 0; j < 4; ++j) sq[j] = zv[j] * zv[j];
#pragma unroll
    for (int off = 8; off < 64; off <<= 1) {
#pragma unroll
        for (int j = 0; j < 4; ++j) {
            zv[j] += __shfl_xor(zv[j], off, 64);
            sq[j] += __shfl_xor(sq[j], off, 64);
        }
    }
    if ((tid & 63) < 8) {
#pragma unroll
        for (int j = 0; j < 4; ++j) {
            atomicAdd(&psum[c0 + j], zv[j]);
            atomicAdd(&psq[c0 + j], sq[j]);
        }
    }
    __syncthreads();
    if (tid < 2 * DIM) {
        float v = (tid < DIM) ? psum[tid] : psq[tid - DIM];
        atomicAdd(&partial[(long)(blockIdx.x >> 6) * 2 * DIM + tid], v);
    }
}

// ------- pool: RAW sums + per-graph node counts (no BN dependency) -------
__global__ __launch_bounds__(256) void pool_kernel(
    const unsigned short* __restrict__ z, const int* __restrict__ batch,
    float* __restrict__ praw, float* __restrict__ cntg)
{
    __shared__ float acc[32][32];
    __shared__ float cntL[32];
    __shared__ int slot[32];
    __shared__ int segg[32];
    __shared__ int nsegS;
    int tid = threadIdx.x;
    for (int i = tid; i < 1024; i += 256) ((float*)acc)[i] = 0.f;
    if (tid < 32) cntL[tid] = 0.f;
    int nodeBase = blockIdx.x * 32;
    if (tid < 32) {
        int nd = nodeBase + tid;
        int gv = batch[nd];
        int flag = (tid == 0) ? 1 : (gv != batch[nd - 1]);
        unsigned long long m = __ballot(flag);
        int s = __popcll(m & ((2ull << tid) - 1ull)) - 1;
        slot[tid] = s;
        if (flag) segg[s] = gv;
        if (tid == 0) nsegS = __popcll(m);
    }
    __syncthreads();

    int ln = tid >> 3;
    int p = tid & 7;
    long node = nodeBase + ln;
    uint2 u = ((const uint2*)z)[node * 8 + p];
    int c = p * 4;
    float2 f01 = up2(u.x), f23 = up2(u.y);
    int s = slot[ln];
    atomicAdd(&acc[s][c+0], f01.x);
    atomicAdd(&acc[s][c+1], f01.y);
    atomicAdd(&acc[s][c+2], f23.x);
    atomicAdd(&acc[s][c+3], f23.y);
    if (p == 0) atomicAdd(&cntL[s], 1.f);
    __syncthreads();

    int total = nsegS * 32;
    for (int i = tid; i < total; i += 256) {
        int r = i >> 5, dd = i & 31;
        float val = acc[r][dd];
        if (val != 0.f) atomicAdd(&praw[(long)segg[r] * DIM + dd], val);
    }
    if (tid < nsegS) atomicAdd(&cntg[segg[tid]], cntL[tid]);
}

// ---- fc: prologue computes layer-4 BN from partial4, then
//      out = relu(bfc + cnt*(shl@Wfc) + (scl.*praw)@Wfc) ----
__global__ __launch_bounds__(256) void fc_kernel(
    const float* __restrict__ praw, const float* __restrict__ cntg,
    const float* __restrict__ partial4,
    const float* __restrict__ g4, const float* __restrict__ be4,
    const float* __restrict__ Wfc, const float* __restrict__ bfc,
    float* __restrict__ out)
{
    __shared__ float Wl[DIM * OUTD];   // 16 KB
    __shared__ float red[256];
    __shared__ float sscl[DIM], sshl[DIM], dvec[OUTD];
    int tid = threadIdx.x;
    for (int i = tid; i < DIM * OUTD; i += 256) Wl[i] = Wfc[i];
    {
        int c = tid & 63, chunk = tid >> 6;
        float a = 0.f;
        for (int p = chunk; p < NSLOTS2; p += 4) a += partial4[p * 64 + c];
        red[tid] = a;
    }
    __syncthreads();
    if (tid < 64) red[tid] = red[tid] + red[tid+64] + red[tid+128] + red[tid+192];
    __syncthreads();
    if (tid < DIM) {
        const float invN = 1.0f / (float)N_NODES;
        float S = red[tid], Q = red[tid + DIM];
        float mu = S * invN;
        float var = Q * invN - mu * mu;
        float sc = g4[tid] * rsqrtf(var + BN_EPS);
        sscl[tid] = sc;
        sshl[tid] = be4[tid] - mu * sc;
    }
    __syncthreads();
    if (tid < OUTD) {
        float dv = 0.f;
        for (int k = 0; k < DIM; ++k) dv = fmaf(sshl[k], Wl[k * OUTD + tid], dv);
        dvec[tid] = dv;
    }
    __syncthreads();
    int t = blockIdx.x * 256 + tid;
    int g = t >> 7;
    int o = t & (OUTD - 1);
    float acc = bfc[o] + cntg[g] * dvec[o];
    const float* pr = praw + (long)g * DIM;
#pragma unroll
    for (int k = 0; k < DIM; ++k)
        acc = fmaf(sscl[k] * pr[k], Wl[k * OUTD + o], acc);
    out[t] = fmaxf(acc, 0.f);
}

extern "C" void kernel_launch(void* const* d_in, const int* in_sizes, int n_in,
                              void* d_out, int out_size, void* d_ws, size_t ws_size,
                              hipStream_t stream) {
    const float* x      = (const float*)d_in[0];
    const int*   ei     = (const int*)  d_in[1];
    const int*   batch  = (const int*)  d_in[2];
    const float* W1_0   = (const float*)d_in[3];
    const float* W1_rest= (const float*)d_in[4];
    const float* b1     = (const float*)d_in[5];
    const float* W2     = (const float*)d_in[6];
    const float* b2     = (const float*)d_in[7];
    const float* gamma  = (const float*)d_in[8];
    const float* beta   = (const float*)d_in[9];
    const float* Wfc    = (const float*)d_in[10];
    const float* bfc    = (const float*)d_in[11];
    float* out = (float*)d_out;

    int* wsi = (int*)d_ws;
    const size_t nf = (size_t)N_NODES * DIM;                   // 3.2M elems
    const size_t BD = (size_t)NBUK * STRIDE;                   // 1,801,728 ints
    const size_t PSTRIDE = (size_t)NSLOTS2 * 2 * DIM;          // 3136 floats
    int*   bdata  = wsi;
    unsigned short* zfpA = (unsigned short*)(wsi + BD);        // 6.4 MB
    unsigned short* zfpB = zfpA + nf;                          // 6.4 MB
    int*   edge_src = (int*)(zfpB + nf);                       // 1.6M ints
    int*   offs   = edge_src + N_EDGES;                        // 100,001
    int*   bcnt   = offs + (N_NODES + 1);                      // 391
    int*   bbase  = bcnt + NBUK;                               // 392
    float* praw   = (float*)(bbase + NBUK + 1);                // 65,536
    float* cntg   = praw + (size_t)N_GRAPHS * DIM;             // 2,048
    float* partial= cntg + N_GRAPHS;                           // 5*3136

    hipMemsetAsync(praw, 0,
        ((size_t)N_GRAPHS * DIM + N_GRAPHS + NLAYERS * PSTRIDE) * sizeof(float),
        stream);
    hipMemsetAsync(bcnt, 0, (size_t)NBUK * sizeof(int), stream);

    const int grpBlocks = (N_NODES * 8) / 256;                 // 3125

    // prep: bucket fill (391 blocks) || gemm1 (3125 blocks)
    prep_kernel<<<NBLK + grpBlocks, 256, 0, stream>>>(
        ei, bcnt, bdata, x, W1_0, zfpA);
    bscan_kernel<<<1, 512, 0, stream>>>(bcnt, bbase);
    cfill2_kernel<<<NBUK, 256, 0, stream>>>(bcnt, bbase, bdata, edge_src, offs);

    // layer 0: gather y0, no matmul fold
    layer_kernel<false><<<N_NODES / NPB, 256, 0, stream>>>(
        offs, edge_src, zfpA, nullptr, nullptr, nullptr, nullptr,
        b1, W2, b2, zfpB, partial);

    // layers 1..4: prologue folds prev BN into W1
    const unsigned short* zi = zfpB;
    unsigned short* zo = zfpA;
    for (int i = 1; i < NLAYERS; ++i) {
        layer_kernel<true><<<N_NODES / NPB, 256, 0, stream>>>(
            offs, edge_src, zi,
            W1_rest + (size_t)(i - 1) * DIM * DIM,
            partial + (size_t)(i - 1) * PSTRIDE,
            gamma + (i - 1) * DIM, beta + (i - 1) * DIM,
            b1 + i * DIM, W2 + (size_t)i * DIM * DIM, b2 + i * DIM,
            zo, partial + (size_t)i * PSTRIDE);
        const unsigned short* tmp = zi; zi = zo; zo = (unsigned short*)tmp;
    }

    // pool raw sums + counts, then fc applies layer-4 BN
    pool_kernel<<<N_NODES / 32, 256, 0, stream>>>(zi, batch, praw, cntg);
    fc_kernel<<<(N_GRAPHS * OUTD) / 256, 256, 0, stream>>>(
        praw, cntg, partial + (size_t)(NLAYERS - 1) * PSTRIDE,
        gamma + (NLAYERS - 1) * DIM, beta + (NLAYERS - 1) * DIM,
        Wfc, bfc, out);
}